// Round 5
// baseline (9.606 us; speedup 1.0000x reference)
//
#include <hip/hip_runtime.h>
#include <math.h>

// Closed-form collapse of the quanv circuit (verified round 4, absmax 0.0):
//  - pre-entanglement rotations folded into the product state
//  - rx w1 / ry w2 / rx w5 commuted past the CNOTs (Heisenberg picture)
//  - 5 CNOTs (Clifford) pull each Z_w back to a Pauli string whose
//    product-state expectation factorizes per wire.
// Per patch (C_w = cos(pixel_w), S_w = sin(pixel_w); cq/sq = cos/sin q):
//   z0 = C0 cq0 - S0 sq0 ; z8 = cq9 C8 - cq5 sq9 S8 ; z6 = cq7 C6
//   E0 = z0 z8          E1 = cq4 z0 C1       E2 = cq6 C2 - sq6 S2 S3
//   E3 = cq1 C2 C3      E4 = C4              E5 = C4 (cq10 C5 + sq10 sq2 S5)
//   E6 = z6             E7 = z6 (cq3 C7 - sq3 S7)   E8 = z8

#define IMG 28
#define NPIX (IMG*IMG)
#define NPP 169            // 13*13 patches per image
#define FEAT 1521          // 169*9

__global__ __launch_bounds__(256) void fused_kernel(
    const float* __restrict__ x, const float* __restrict__ qp,
    const float* __restrict__ W, const float* __restrict__ bias,
    float* __restrict__ out)
{
    __shared__ float csA[NPIX], snA[NPIX];
    __shared__ float red0[4], red1[4];

    const int img = blockIdx.x;
    const int tid = threadIdx.x;

    // per-pixel full-angle trig; float4 vector loads (784 = 196*4)
    const float4* xi4 = (const float4*)(x + img * NPIX);
    for (int i = tid; i < NPIX / 4; i += 256) {
        float4 v = xi4[i];
        float s, c;
        __sincosf(v.x, &s, &c); csA[4*i+0] = c; snA[4*i+0] = s;
        __sincosf(v.y, &s, &c); csA[4*i+1] = c; snA[4*i+1] = s;
        __sincosf(v.z, &s, &c); csA[4*i+2] = c; snA[4*i+2] = s;
        __sincosf(v.w, &s, &c); csA[4*i+3] = c; snA[4*i+3] = s;
    }

    // full-angle parameter trig (uniform, cheap)
    float cq[11], sq[11];
    #pragma unroll
    for (int p = 0; p < 11; ++p)
        __sincosf(qp[p], &sq[p], &cq[p]);

    __syncthreads();

    float s0 = 0.0f, s1 = 0.0f;
    if (tid < NPP) {
        const int pr = tid / 13;
        const int pc = tid - pr * 13;
        const int base = (pr * 2) * IMG + pc * 2;

        float C[9], S[9];
        #pragma unroll
        for (int a = 0; a < 3; ++a)
            #pragma unroll
            for (int c = 0; c < 3; ++c) {
                int ix = base + a * IMG + c;
                C[a*3+c] = csA[ix];
                S[a*3+c] = snA[ix];
            }

        const float z0 = C[0]*cq[0] - S[0]*sq[0];
        const float z8 = cq[9]*C[8] - cq[5]*sq[9]*S[8];
        const float z6 = cq[7]*C[6];

        float E[9];
        E[0] = z0 * z8;
        E[1] = cq[4] * z0 * C[1];
        E[2] = cq[6]*C[2] - sq[6]*S[2]*S[3];
        E[3] = cq[1]*C[2]*C[3];
        E[4] = C[4];
        E[5] = C[4]*(cq[10]*C[5] + sq[10]*sq[2]*S[5]);
        E[6] = z6;
        E[7] = z6*(cq[3]*C[7] - sq[3]*S[7]);
        E[8] = z8;

        // W is L2-resident (reused by all 1024 blocks); read direct.
        const float* W0 = W + tid * 9;
        const float* W1 = W + FEAT + tid * 9;
        #pragma unroll
        for (int w = 0; w < 9; ++w) {
            s0 += E[w] * W0[w];
            s1 += E[w] * W1[w];
        }
    }

    // block reduction: wave butterfly then cross-wave via LDS
    #pragma unroll
    for (int m = 1; m < 64; m <<= 1) {
        s0 += __shfl_xor(s0, m);
        s1 += __shfl_xor(s1, m);
    }
    const int wv = tid >> 6;
    if ((tid & 63) == 0) { red0[wv] = s0; red1[wv] = s1; }
    __syncthreads();
    if (tid == 0) {
        float l0 = red0[0] + red0[1] + red0[2] + red0[3] + bias[0];
        float l1 = red1[0] + red1[1] + red1[2] + red1[3] + bias[1];
        float mx  = fmaxf(l0, l1);
        float lse = mx + __logf(__expf(l0 - mx) + __expf(l1 - mx));
        out[img * 2 + 0] = l0 - lse;
        out[img * 2 + 1] = l1 - lse;
    }
}

extern "C" void kernel_launch(void* const* d_in, const int* in_sizes, int n_in,
                              void* d_out, int out_size, void* d_ws, size_t ws_size,
                              hipStream_t stream) {
    const float* x  = (const float*)d_in[0];   // (1024,1,28,28)
    const float* qp = (const float*)d_in[1];   // (11,)
    const float* W  = (const float*)d_in[2];   // (2,1521)
    const float* b  = (const float*)d_in[3];   // (2,)
    float* out = (float*)d_out;                // (1024,2) f32

    fused_kernel<<<1024, 256, 0, stream>>>(x, qp, W, b, out);
}